// Round 1
// baseline (204.673 us; speedup 1.0000x reference)
//
#include <hip/hip_runtime.h>
#include <stdint.h>

typedef __attribute__((ext_vector_type(8))) short short8;
typedef __attribute__((ext_vector_type(4))) float f32x4;

#define NN    784              // 28*28
#define NKT   25               // K tiles of 32 (784 padded to 800)
#define BM    64               // batch rows per block
#define BTILE_B (NN*32*2)      // 50176 bytes per B K-tile

__device__ __forceinline__ unsigned short f2bf(float f) {
  unsigned int u = __float_as_uint(f);
  return (unsigned short)((u + 0x7FFFu + ((u >> 16) & 1u)) >> 16);  // RNE, finite inputs
}

// Build Bpack[t][n][kk] = weight[n] * W[n][j=t*32+kk]  (bf16), zero for j>=784.
// W[i][j] = exp(min(ep[j],0) * d2(i,j)) * (d2 < 9), d2 between grid(i) and pos2d(j).
// grid[a,b] = (b, a)  (meshgrid xy indexing).
__global__ void build_w_kernel(const float* __restrict__ pos2d,
                               const float* __restrict__ weight,
                               const float* __restrict__ ep,
                               unsigned short* __restrict__ Bpack) {
  int idx = blockIdx.x * 256 + threadIdx.x;   // 0 .. 25*784*32-1
  int kk   = idx & 31;
  int rest = idx >> 5;                        // t*784 + n
  int n = rest % NN;
  int t = rest / NN;
  int j = t * 32 + kk;
  float val = 0.f;
  if (j < NN) {
    int a = n / 28, b = n - a * 28;           // output cell (row i = n of W)
    float px = pos2d[2 * j + 0];
    float py = pos2d[2 * j + 1];
    float dx = (float)b - px;
    float dy = (float)a - py;
    float d2 = __fadd_rn(__fmul_rn(dx, dx), __fmul_rn(dy, dy));  // match np exactly (no fma)
    if (d2 < 9.0f) {
      float en = fminf(ep[j], 0.f);
      val = expf(en * d2) * weight[n];
    }
  }
  Bpack[idx] = f2bf(val);
}

__global__ __launch_bounds__(512, 2)
void gemm_kernel(const float* __restrict__ x,
                 const unsigned short* __restrict__ Bpack,
                 float* __restrict__ out) {
  __shared__ unsigned short Blds[2][NN * 32];   // 50176 B each buffer
  __shared__ unsigned short Alds[2][BM * 32];   //  4096 B each buffer

  const int tid  = threadIdx.x;
  const int wave = tid >> 6;
  const int lane = tid & 63;
  const int m0   = blockIdx.x * BM;

  // 49 n-fragments over 8 waves: wave0 -> 7 frags [0..6], waves1..7 -> 6 frags
  const int f0 = (wave == 0) ? 0 : (6 * wave + 1);

  f32x4 acc[4][7];
  #pragma unroll
  for (int mf = 0; mf < 4; ++mf)
    #pragma unroll
    for (int f = 0; f < 7; ++f) acc[mf][f] = (f32x4){0.f, 0.f, 0.f, 0.f};

  // A staging mapping: thread -> (row, 4 consecutive k)
  const int arow = tid >> 3;            // 0..63
  const int akc  = (tid & 7) << 2;      // 0,4,...,28
  const float* xrow = x + (size_t)(m0 + arow) * NN;

  auto stageA = [&](int buf, int t) {
    int k = t * 32 + akc;
    f32x4 v = (f32x4){0.f, 0.f, 0.f, 0.f};
    if (k < NN) v = *(const f32x4*)(xrow + k);          // 784%4==0 -> full vector valid
    ushort4 h;
    h.x = f2bf(v.x); h.y = f2bf(v.y); h.z = f2bf(v.z); h.w = f2bf(v.w);
    *(ushort4*)&Alds[buf][arow * 32 + akc] = h;         // ds_write_b64
  };

  auto stageB = [&](int buf, int t) {
    const char* src = (const char*)Bpack + (size_t)t * BTILE_B + lane * 16;
    char* dst = (char*)&Blds[buf][0];
    #pragma unroll
    for (int i = 0; i < 6; ++i) {
      int off = (i * 8 + wave) * 1024;
      __builtin_amdgcn_global_load_lds(
          (const __attribute__((address_space(1))) uint32_t*)(src + off),
          (__attribute__((address_space(3))) uint32_t*)(uintptr_t)(dst + off),
          16, 0, 0);
    }
    if (wave == 0) {                                    // 49th 1 KB chunk
      int off = 48 * 1024;
      __builtin_amdgcn_global_load_lds(
          (const __attribute__((address_space(1))) uint32_t*)(src + off),
          (__attribute__((address_space(3))) uint32_t*)(uintptr_t)(dst + off),
          16, 0, 0);
    }
  };

  stageA(0, 0);
  stageB(0, 0);
  __syncthreads();

  for (int t = 0; t < NKT; ++t) {
    int cur = t & 1;
    if (t + 1 < NKT) { stageB(cur ^ 1, t + 1); stageA(cur ^ 1, t + 1); }

    short8 afr[4];
    #pragma unroll
    for (int mf = 0; mf < 4; ++mf)
      afr[mf] = *(const short8*)&Alds[cur][(mf * 16 + (lane & 15)) * 32 + (lane >> 4) * 8];

    #pragma unroll
    for (int f = 0; f < 7; ++f) {
      int nf = (wave == 0 || f < 6) ? (f0 + f) : 0;     // dummy frag for uniform unroll
      short8 bfr = *(const short8*)&Blds[cur][(nf * 16 + (lane & 15)) * 32 + (lane >> 4) * 8];
      #pragma unroll
      for (int mf = 0; mf < 4; ++mf)
        acc[mf][f] = __builtin_amdgcn_mfma_f32_16x16x32_bf16(afr[mf], bfr, acc[mf][f], 0, 0, 0);
    }
    __syncthreads();
  }

  // Epilogue: C frag mapping col = lane&15, row = (lane>>4)*4 + reg
  const int cgrp = lane >> 4;
  const int ccol = lane & 15;
  #pragma unroll
  for (int f = 0; f < 7; ++f) {
    if (wave != 0 && f == 6) break;                     // wave-uniform
    int col = (f0 + f) * 16 + ccol;
    #pragma unroll
    for (int mf = 0; mf < 4; ++mf) {
      int row = m0 + mf * 16 + cgrp * 4;
      f32x4 a = acc[mf][f];
      out[(size_t)(row + 0) * NN + col] = a.x;
      out[(size_t)(row + 1) * NN + col] = a.y;
      out[(size_t)(row + 2) * NN + col] = a.z;
      out[(size_t)(row + 3) * NN + col] = a.w;
    }
  }
}

extern "C" void kernel_launch(void* const* d_in, const int* in_sizes, int n_in,
                              void* d_out, int out_size, void* d_ws, size_t ws_size,
                              hipStream_t stream) {
  const float* x      = (const float*)d_in[0];
  const float* pos2d  = (const float*)d_in[1];
  const float* weight = (const float*)d_in[2];
  const float* ep     = (const float*)d_in[3];
  float* out          = (float*)d_out;
  unsigned short* Bpack = (unsigned short*)d_ws;        // 25*784*32*2 = 1,254,400 B

  int batch = in_sizes[0] / NN;                         // 65536

  build_w_kernel<<<dim3((NKT * NN * 32) / 256), dim3(256), 0, stream>>>(pos2d, weight, ep, Bpack);
  gemm_kernel<<<dim3(batch / BM), dim3(512), 0, stream>>>(x, Bpack, out);
}

// Round 2
// 202.454 us; speedup vs baseline: 1.0110x; 1.0110x over previous
//
#include <hip/hip_runtime.h>
#include <stdint.h>

typedef __attribute__((ext_vector_type(8))) short short8;
typedef __attribute__((ext_vector_type(4))) float f32x4;

#define NN    784              // 28*28
#define NKT   25               // K tiles of 32 (784 padded to 800)
#define BM    64               // batch rows per block
#define BTILE_B (NN*32*2)      // 50176 bytes per B K-tile

__device__ __forceinline__ unsigned short f2bf(float f) {
  unsigned int u = __float_as_uint(f);
  return (unsigned short)((u + 0x7FFFu + ((u >> 16) & 1u)) >> 16);  // RNE, finite inputs
}

// XOR-swizzle: spread 64B-stride rows across the 8 16B bank-positions.
// byte layout: row = b>>6, chunk = (b>>4)&3. chunk ^= (row>>1)&3  -> 2-way (free).
__device__ __forceinline__ int swz(int b) { return b ^ (((b >> 7) & 3) << 4); }

// Build Bpack[t][swz(n,kk)] = weight[n] * W[n][j=t*32+kk]  (bf16), zero for j>=784.
// Layout is PRE-SWIZZLED so that linear global_load_lds staging lands the
// swizzled layout in LDS (rule: swizzle both sides or neither).
__global__ void build_w_kernel(const float* __restrict__ pos2d,
                               const float* __restrict__ weight,
                               const float* __restrict__ ep,
                               unsigned short* __restrict__ Bpack) {
  int idx = blockIdx.x * 256 + threadIdx.x;   // 0 .. 25*784*32-1
  int kk   = idx & 31;
  int rest = idx >> 5;                        // t*784 + n
  int n = rest % NN;
  int t = rest / NN;
  int j = t * 32 + kk;
  float val = 0.f;
  if (j < NN) {
    int a = n / 28, b = n - a * 28;           // output cell (row i = n of W)
    float px = pos2d[2 * j + 0];
    float py = pos2d[2 * j + 1];
    float dx = (float)b - px;
    float dy = (float)a - py;
    float d2 = __fadd_rn(__fmul_rn(dx, dx), __fmul_rn(dy, dy));  // match np exactly (no fma)
    if (d2 < 9.0f) {
      float en = fminf(ep[j], 0.f);
      val = expf(en * d2) * weight[n];
    }
  }
  int b_in_tile = n * 64 + kk * 2;            // byte offset inside one K-tile
  int dst = t * (NN * 32) + (swz(b_in_tile) >> 1);
  Bpack[dst] = f2bf(val);
}

__global__ __launch_bounds__(1024, 4)
void gemm_kernel(const float* __restrict__ x,
                 const unsigned short* __restrict__ Bpack,
                 float* __restrict__ out) {
  __shared__ unsigned short Blds[2][NN * 32];   // 50176 B each buffer
  __shared__ unsigned short Alds[2][BM * 32];   //  4096 B each buffer

  const int tid  = threadIdx.x;
  const int wave = tid >> 6;
  const int lane = tid & 63;
  const int m0   = blockIdx.x * BM;

  const int wm = wave >> 3;       // 0..1  -> m-frags {2*wm, 2*wm+1}
  const int wn = wave & 7;        // 0..7  -> n-frag group
  const int nF = (wn == 0) ? 7 : 6;
  const int f0 = (wn == 0) ? 0 : (6 * wn + 1);

  f32x4 acc[2][7];
  #pragma unroll
  for (int mf = 0; mf < 2; ++mf)
    #pragma unroll
    for (int f = 0; f < 7; ++f) acc[mf][f] = (f32x4){0.f, 0.f, 0.f, 0.f};

  // A staging: 64 rows x 32 k over 1024 threads -> 2 consecutive k each
  const int arow = tid >> 4;            // 0..63
  const int akc  = (tid & 15) << 1;     // 0,2,...,30
  const float* xrow = x + (size_t)(m0 + arow) * NN;

  auto stageA = [&](int buf, int t) {
    int k = t * 32 + akc;
    float vx = 0.f, vy = 0.f;
    if (k < NN) { vx = xrow[k]; vy = xrow[k + 1]; }     // NN even -> pair valid together
    ushort2 h; h.x = f2bf(vx); h.y = f2bf(vy);
    int b = arow * 64 + akc * 2;
    *(ushort2*)((char*)&Alds[buf][0] + swz(b)) = h;     // ds_write_b32, swizzled
  };

  auto stageB = [&](int buf, int t) {
    const char* src = (const char*)Bpack + (size_t)t * BTILE_B + lane * 16;
    char* dst = (char*)&Blds[buf][0];
    #pragma unroll
    for (int i = 0; i < 3; ++i) {                       // 16 waves x 3 = 48 chunks
      int off = (i * 16 + wave) * 1024;
      __builtin_amdgcn_global_load_lds(
          (const __attribute__((address_space(1))) uint32_t*)(src + off),
          (__attribute__((address_space(3))) uint32_t*)(uintptr_t)(dst + off),
          16, 0, 0);
    }
    if (wave == 0) {                                    // 49th 1 KB chunk
      int off = 48 * 1024;
      __builtin_amdgcn_global_load_lds(
          (const __attribute__((address_space(1))) uint32_t*)(src + off),
          (__attribute__((address_space(3))) uint32_t*)(uintptr_t)(dst + off),
          16, 0, 0);
    }
  };

  stageA(0, 0);
  stageB(0, 0);
  __syncthreads();

  for (int t = 0; t < NKT; ++t) {
    int cur = t & 1;
    if (t + 1 < NKT) { stageB(cur ^ 1, t + 1); stageA(cur ^ 1, t + 1); }

    short8 afr[2];
    #pragma unroll
    for (int mf = 0; mf < 2; ++mf) {
      int row = (wm * 2 + mf) * 16 + (lane & 15);
      int b = row * 64 + (lane >> 4) * 16;
      afr[mf] = *(const short8*)((char*)&Alds[cur][0] + swz(b));
    }

    #pragma unroll
    for (int f = 0; f < 7; ++f) {
      if (f < nF) {                                     // wave-uniform guard
        int row = (f0 + f) * 16 + (lane & 15);
        int b = row * 64 + (lane >> 4) * 16;
        short8 bfr = *(const short8*)((char*)&Blds[cur][0] + swz(b));
        acc[0][f] = __builtin_amdgcn_mfma_f32_16x16x32_bf16(afr[0], bfr, acc[0][f], 0, 0, 0);
        acc[1][f] = __builtin_amdgcn_mfma_f32_16x16x32_bf16(afr[1], bfr, acc[1][f], 0, 0, 0);
      }
    }
    __syncthreads();
  }

  // Epilogue: C frag mapping col = lane&15, row = (lane>>4)*4 + reg
  const int cgrp = lane >> 4;
  const int ccol = lane & 15;
  #pragma unroll
  for (int f = 0; f < 7; ++f) {
    if (f < nF) {
      int col = (f0 + f) * 16 + ccol;
      #pragma unroll
      for (int mf = 0; mf < 2; ++mf) {
        int row = m0 + (wm * 2 + mf) * 16 + cgrp * 4;
        f32x4 a = acc[mf][f];
        out[(size_t)(row + 0) * NN + col] = a.x;
        out[(size_t)(row + 1) * NN + col] = a.y;
        out[(size_t)(row + 2) * NN + col] = a.z;
        out[(size_t)(row + 3) * NN + col] = a.w;
      }
    }
  }
}

extern "C" void kernel_launch(void* const* d_in, const int* in_sizes, int n_in,
                              void* d_out, int out_size, void* d_ws, size_t ws_size,
                              hipStream_t stream) {
  const float* x      = (const float*)d_in[0];
  const float* pos2d  = (const float*)d_in[1];
  const float* weight = (const float*)d_in[2];
  const float* ep     = (const float*)d_in[3];
  float* out          = (float*)d_out;
  unsigned short* Bpack = (unsigned short*)d_ws;        // 25*784*32*2 = 1,254,400 B

  int batch = in_sizes[0] / NN;                         // 65536

  build_w_kernel<<<dim3((NKT * NN * 32) / 256), dim3(256), 0, stream>>>(pos2d, weight, ep, Bpack);
  gemm_kernel<<<dim3(batch / BM), dim3(1024), 0, stream>>>(x, Bpack, out);
}

// Round 3
// 202.037 us; speedup vs baseline: 1.0130x; 1.0021x over previous
//
#include <hip/hip_runtime.h>
#include <stdint.h>

typedef __attribute__((ext_vector_type(8))) short short8;
typedef __attribute__((ext_vector_type(4))) float f32x4;

#define NN    784              // 28*28
#define NKT   25               // K tiles of 32 (784 padded to 800)
#define BM    64               // batch rows per block
#define BTILE_B (NN*32*2)      // 50176 bytes per B K-tile

__device__ __forceinline__ unsigned short f2bf(float f) {
  unsigned int u = __float_as_uint(f);
  return (unsigned short)((u + 0x7FFFu + ((u >> 16) & 1u)) >> 16);  // RNE, finite inputs
}

// XOR-swizzle: spread 64B-stride rows across the 8 16B bank-positions.
// byte layout: row = b>>6, chunk = (b>>4)&3. chunk ^= (row>>1)&3  -> 2-way (free).
__device__ __forceinline__ int swz(int b) { return b ^ (((b >> 7) & 3) << 4); }

// Build Bpack[t][swz(n,kk)] = weight[n] * W[n][j=t*32+kk]  (bf16), zero for j>=784.
// Layout is PRE-SWIZZLED so that linear global_load_lds staging lands the
// swizzled layout in LDS (rule: swizzle both sides or neither).
__global__ void build_w_kernel(const float* __restrict__ pos2d,
                               const float* __restrict__ weight,
                               const float* __restrict__ ep,
                               unsigned short* __restrict__ Bpack) {
  int idx = blockIdx.x * 256 + threadIdx.x;   // 0 .. 25*784*32-1
  int kk   = idx & 31;
  int rest = idx >> 5;                        // t*784 + n
  int n = rest % NN;
  int t = rest / NN;
  int j = t * 32 + kk;
  float val = 0.f;
  if (j < NN) {
    int a = n / 28, b = n - a * 28;           // output cell (row i = n of W)
    float px = pos2d[2 * j + 0];
    float py = pos2d[2 * j + 1];
    float dx = (float)b - px;
    float dy = (float)a - py;
    float d2 = __fadd_rn(__fmul_rn(dx, dx), __fmul_rn(dy, dy));  // match np exactly (no fma)
    if (d2 < 9.0f) {
      float en = fminf(ep[j], 0.f);
      val = expf(en * d2) * weight[n];
    }
  }
  int b_in_tile = n * 64 + kk * 2;            // byte offset inside one K-tile
  int dst = t * (NN * 32) + (swz(b_in_tile) >> 1);
  Bpack[dst] = f2bf(val);
}

__global__ __launch_bounds__(1024, 4)
void gemm_kernel(const float* __restrict__ x,
                 const unsigned short* __restrict__ Bpack,
                 float* __restrict__ out) {
  __shared__ unsigned short Blds[2][NN * 32];   // 50176 B each buffer
  __shared__ unsigned short Alds[2][BM * 32];   //  4096 B each buffer

  const int tid  = threadIdx.x;
  const int wave = tid >> 6;
  const int lane = tid & 63;
  const int m0   = blockIdx.x * BM;

  const int wm = wave >> 3;       // 0..1  -> m-frags {2*wm, 2*wm+1}
  const int wn = wave & 7;        // 0..7  -> n-frag group
  const int nF = (wn == 0) ? 7 : 6;
  const int f0 = (wn == 0) ? 0 : (6 * wn + 1);

  f32x4 acc[2][7];
  #pragma unroll
  for (int mf = 0; mf < 2; ++mf)
    #pragma unroll
    for (int f = 0; f < 7; ++f) acc[mf][f] = (f32x4){0.f, 0.f, 0.f, 0.f};

  // A staging: 64 rows x 32 k over 1024 threads -> 2 consecutive k each
  const int arow = tid >> 4;            // 0..63
  const int akc  = (tid & 15) << 1;     // 0,2,...,30
  const float* xrow = x + (size_t)(m0 + arow) * NN;

  auto stageA = [&](int buf, int t) {
    int k = t * 32 + akc;
    float vx = 0.f, vy = 0.f;
    if (k < NN) { vx = xrow[k]; vy = xrow[k + 1]; }     // NN even -> pair valid together
    ushort2 h; h.x = f2bf(vx); h.y = f2bf(vy);
    int b = arow * 64 + akc * 2;
    *(ushort2*)((char*)&Alds[buf][0] + swz(b)) = h;     // ds_write_b32, swizzled
  };

  auto stageB = [&](int buf, int t) {
    const char* src = (const char*)Bpack + (size_t)t * BTILE_B + lane * 16;
    char* dst = (char*)&Blds[buf][0];
    #pragma unroll
    for (int i = 0; i < 3; ++i) {                       // 16 waves x 3 = 48 chunks
      int off = (i * 16 + wave) * 1024;
      __builtin_amdgcn_global_load_lds(
          (const __attribute__((address_space(1))) uint32_t*)(src + off),
          (__attribute__((address_space(3))) uint32_t*)(uintptr_t)(dst + off),
          16, 0, 0);
    }
    if (wave == 0) {                                    // 49th 1 KB chunk
      int off = 48 * 1024;
      __builtin_amdgcn_global_load_lds(
          (const __attribute__((address_space(1))) uint32_t*)(src + off),
          (__attribute__((address_space(3))) uint32_t*)(uintptr_t)(dst + off),
          16, 0, 0);
    }
  };

  stageA(0, 0);
  stageB(0, 0);
  __syncthreads();

  for (int t = 0; t < NKT; ++t) {
    int cur = t & 1;
    if (t + 1 < NKT) { stageB(cur ^ 1, t + 1); stageA(cur ^ 1, t + 1); }

    short8 afr[2];
    #pragma unroll
    for (int mf = 0; mf < 2; ++mf) {
      int row = (wm * 2 + mf) * 16 + (lane & 15);
      int b = row * 64 + (lane >> 4) * 16;
      afr[mf] = *(const short8*)((char*)&Alds[cur][0] + swz(b));
    }

    #pragma unroll
    for (int f = 0; f < 7; ++f) {
      if (f < nF) {                                     // wave-uniform guard
        int row = (f0 + f) * 16 + (lane & 15);
        int b = row * 64 + (lane >> 4) * 16;
        short8 bfr = *(const short8*)((char*)&Blds[cur][0] + swz(b));
        acc[0][f] = __builtin_amdgcn_mfma_f32_16x16x32_bf16(afr[0], bfr, acc[0][f], 0, 0, 0);
        acc[1][f] = __builtin_amdgcn_mfma_f32_16x16x32_bf16(afr[1], bfr, acc[1][f], 0, 0, 0);
      }
    }
    __syncthreads();
  }

  // Epilogue: C frag mapping col = lane&15, row = (lane>>4)*4 + reg
  const int cgrp = lane >> 4;
  const int ccol = lane & 15;
  #pragma unroll
  for (int f = 0; f < 7; ++f) {
    if (f < nF) {
      int col = (f0 + f) * 16 + ccol;
      #pragma unroll
      for (int mf = 0; mf < 2; ++mf) {
        int row = m0 + (wm * 2 + mf) * 16 + cgrp * 4;
        f32x4 a = acc[mf][f];
        out[(size_t)(row + 0) * NN + col] = a.x;
        out[(size_t)(row + 1) * NN + col] = a.y;
        out[(size_t)(row + 2) * NN + col] = a.z;
        out[(size_t)(row + 3) * NN + col] = a.w;
      }
    }
  }
}

extern "C" void kernel_launch(void* const* d_in, const int* in_sizes, int n_in,
                              void* d_out, int out_size, void* d_ws, size_t ws_size,
                              hipStream_t stream) {
  const float* x      = (const float*)d_in[0];
  const float* pos2d  = (const float*)d_in[1];
  const float* weight = (const float*)d_in[2];
  const float* ep     = (const float*)d_in[3];
  float* out          = (float*)d_out;
  unsigned short* Bpack = (unsigned short*)d_ws;        // 25*784*32*2 = 1,254,400 B

  int batch = in_sizes[0] / NN;                         // 65536

  build_w_kernel<<<dim3((NKT * NN * 32) / 256), dim3(256), 0, stream>>>(pos2d, weight, ep, Bpack);
  gemm_kernel<<<dim3(batch / BM), dim3(1024), 0, stream>>>(x, Bpack, out);
}